// Round 8
// baseline (137.533 us; speedup 1.0000x reference)
//
#include <hip/hip_runtime.h>
#include <hip/hip_bf16.h>

// LoRA-factored 3x3 conv. out fp32. Input dtypes runtime-detected.
// x: [16,128,56,56], A: [256,16], B: [16,1152] -> out: [16,256,56,56]
// R12: R11's MFMA stage-1 kept, but its 8-per-lane u16 channel gathers
// (FETCH 72MB, 2.2TB/s gather-bound) are replaced by a one-shot global
// transpose: xt[b][h+1][w+1][c] bf16 with ZERO-PADDED borders. K-step =
// one aligned 16B load (8 consecutive channels) + 2 MFMA (B hi+lo bf16
// split). No validity masks (padding). cb-steps sweep each pixel's 256B
// channel block sequentially -> full line use, L1-hot across 9 taps.
// Paths: ws>=13.9MB -> transpose+MFMA; ws>=90KB -> R10 VALU kernel (48us,
// proven); else fallback.

#define Bn 16
#define Cc 128
#define Hh 56
#define Ww 56
#define Ll (Hh * Ww)      // 3136
#define Rr 16
#define Oo 256
#define KF (Cc * 9)       // 1152
#define NKS 36            // K-steps: 1152/32
#define H2 (Hh + 2)       // 58
#define W2 (Ww + 2)       // 58
#define HB 2              // rows/block (mid path)

typedef __attribute__((ext_vector_type(8))) short bfrag_t;  // 8 bf16 (4 VGPR)
typedef __attribute__((ext_vector_type(4))) float f32x4;    // C frag

__device__ __forceinline__ float bf16_bits(unsigned short u) {
    return __uint_as_float(((unsigned)u) << 16);
}

__device__ __forceinline__ unsigned short bf16_rne(float f) {
    const unsigned u = __float_as_uint(f);
    const unsigned r = u + 0x7FFFu + ((u >> 16) & 1u);
    return (unsigned short)(r >> 16);
}

template<bool BF>
__device__ __forceinline__ float ld(const void* __restrict__ p, unsigned i) {
    if constexpr (BF) return bf16_bits(((const unsigned short*)p)[i]);
    else              return ((const float*)p)[i];
}

// bf16-packed: bits14..7 of each dword = a bf16 exponent (~[96,144]) -> 32/32.
// fp32: uniform mantissa bits -> ~6/32. Threshold 20. (Proven R3.)
__device__ __forceinline__ bool detect_bf16(const void* __restrict__ p) {
    const unsigned* w = (const unsigned*)p;
    int c = 0;
#pragma unroll
    for (int i = 0; i < 32; ++i) {
        const unsigned e = (w[i] >> 7) & 0xFFu;
        c += (e >= 96u && e <= 144u) ? 1 : 0;
    }
    return c >= 20;
}

// ---- prep (MFMA path): Bfrag[kstep][hi/lo][lane][8e] bf16 (frag order,
//      tap-major K), Afp[o][r] fp32.
__global__ __launch_bounds__(256) void prep_frag(
    const void* __restrict__ A, const void* __restrict__ Bm,
    unsigned short* __restrict__ Bfrag, float* __restrict__ Afp)
{
    const bool ab = detect_bf16(A);
    const bool bb = detect_bf16(Bm);
    const int i = blockIdx.x * 256 + threadIdx.x;
    if (i < NKS * 512) {
        const int kstep = i >> 9, rem = i & 511;
        const int l = rem >> 3, e = rem & 7;
        const int r = l & 15, g = l >> 4;
        const int kp = kstep * 32 + g * 8 + e;   // tap-major k'
        const int tap = kp >> 7, c = kp & 127;
        const int k = c * 9 + tap;               // torch Unfold order (c,kh,kw)
        const float v = bb ? bf16_bits(((const unsigned short*)Bm)[r * KF + k])
                           : ((const float*)Bm)[r * KF + k];
        const unsigned short hi = bf16_rne(v);
        const float lov = v - bf16_bits(hi);
        Bfrag[(kstep * 2 + 0) * 512 + rem] = hi;
        Bfrag[(kstep * 2 + 1) * 512 + rem] = bf16_rne(lov);
    }
    if (i < Oo * Rr) {
        Afp[i] = ab ? bf16_bits(((const unsigned short*)A)[i])
                    : ((const float*)A)[i];
    }
}

// ---- transpose: x[b][c][h][w] -> xt[b][h+1][w+1][c] bf16, borders zeroed.
__global__ __launch_bounds__(256) void transpose_x(
    const void* __restrict__ x, unsigned short* __restrict__ xt)
{
    __shared__ unsigned short tile[Cc][Ww + 1];   // [128][57] u16, 14.6 KB
    const bool xb = detect_bf16(x);
    const int tid = threadIdx.x;
    const int h2  = blockIdx.x;          // 0..57
    const int b   = blockIdx.y;
    const unsigned rowbase = (unsigned)(((b * H2 + h2) * W2) * Cc);  // elem idx
    unsigned* xtw = (unsigned*)xt;
    if (h2 == 0 || h2 == H2 - 1) {
        // zero border row: 58*128 elems = 3712 dwords
        for (int i = tid; i < W2 * Cc / 2; i += 256)
            xtw[rowbase / 2 + i] = 0u;
        return;
    }
    const int h = h2 - 1;
    // phase A: read x (w-coalesced), store tile[c][w]
    const unsigned xrow = (unsigned)(b * Cc * Ll + h * Ww);
#pragma unroll 4
    for (int it = 0; it < 32; ++it) {
        const int i = it * 256 + tid;     // 8192 = 128 c x 64 wpad
        const int c = i >> 6, wl = i & 63;
        if (wl < Ww) {
            unsigned short v;
            if (xb) v = ((const unsigned short*)x)[xrow + (unsigned)c * Ll + (unsigned)wl];
            else    v = bf16_rne(((const float*)x)[xrow + (unsigned)c * Ll + (unsigned)wl]);
            tile[c][wl] = v;
        }
    }
    __syncthreads();
    // phase B: write xt interior, c-fast (coalesced u16)
#pragma unroll 4
    for (int it = 0; it < 28; ++it) {
        const int j = it * 256 + tid;      // 7168 = 56 w x 128 c
        const int c = j & 127, w = j >> 7;
        xt[rowbase + (unsigned)((w + 1) * Cc + c)] = tile[c][w];
    }
    // zero w borders (w2 = 0 and 57): 128 u16 each = 64 dwords each
    if (tid < 64)
        xtw[rowbase / 2 + tid] = 0u;
    else if (tid < 128)
        xtw[(rowbase + (unsigned)((W2 - 1) * Cc)) / 2 + (tid - 64)] = 0u;
}

// ---- main (MFMA path): one block = one (b,h) row. 4 waves = 4 px-tiles.
__global__ __launch_bounds__(256, 4) void fused_mfma2(
    const unsigned short* __restrict__ xt,
    const unsigned short* __restrict__ Bfrag,
    const float* __restrict__ Afp,
    float* __restrict__ out)
{
    __shared__ float tmp[Rr][66];   // 4224 B, conflict-free both phases
    const int tid  = threadIdx.x;
    const int lane = tid & 63;
    const int wv   = __builtin_amdgcn_readfirstlane(tid >> 6);  // px-tile 0..3
    const int col  = lane & 15;
    const int g    = lane >> 4;
    const int h    = blockIdx.x;
    const int b    = blockIdx.y;
    const int px   = wv * 16 + col;             // output pixel w (valid < 56)
    const int pxc  = px < Ww ? px : Ww - 1;     // clamp lanes 56..63 (masked)

    // 9 tap element-bases into padded xt: row h+dh, col pxc+dw (always valid)
    unsigned tb[9];
#pragma unroll
    for (int dh = 0; dh < 3; ++dh)
#pragma unroll
        for (int dw = 0; dw < 3; ++dw)
            tb[dh * 3 + dw] =
                (unsigned)(((b * H2 + h + dh) * W2 + pxc + dw) * Cc);

    f32x4 acc = {0.f, 0.f, 0.f, 0.f};
    const bfrag_t* __restrict__ bf = (const bfrag_t*)Bfrag;
    const unsigned ge = (unsigned)(g * 8);

#pragma unroll
    for (int ks = 0; ks < NKS; ++ks) {
        const int tap = ks >> 2, cb = ks & 3;   // cb inner: sequential 64B sweeps
        const bfrag_t pf = *(const bfrag_t*)(xt + tb[tap] + (unsigned)(cb * 32) + ge);
        const bfrag_t ahi = bf[(ks * 2 + 0) * 64 + lane];  // coalesced 16B/lane
        const bfrag_t alo = bf[(ks * 2 + 1) * 64 + lane];
        acc = __builtin_amdgcn_mfma_f32_16x16x32_bf16(ahi, pf, acc, 0, 0, 0);
        acc = __builtin_amdgcn_mfma_f32_16x16x32_bf16(alo, pf, acc, 0, 0, 0);
    }

    // C -> LDS: col=lane&15 (px), row=(lane>>4)*4+reg  [m89]
#pragma unroll
    for (int reg = 0; reg < 4; ++reg)
        tmp[g * 4 + reg][wv * 16 + col] = acc[reg];
    __syncthreads();

    // stage 2 (proven fp32 epilogue): wave wv emits o = wv*64 .. +63
    float tv[Rr];
#pragma unroll
    for (int r = 0; r < Rr; ++r) tv[r] = tmp[r][lane];

    const bool wok = (lane < Ww);
    const size_t obase = (size_t)b * Oo * Ll + (size_t)(h * Ww) + (size_t)lane;
#pragma unroll 4
    for (int j = 0; j < 64; ++j) {
        const int o = wv * 64 + j;
        const float* Ao = Afp + (size_t)o * Rr;   // uniform -> s_load
        float s = 0.f;
#pragma unroll
        for (int r = 0; r < Rr; ++r) s += Ao[r] * tv[r];
        if (wok) out[obase + (size_t)o * Ll] = s;
    }
}

// ================= mid path (ws >= 90KB only): R10's proven VALU kernel ====
__global__ __launch_bounds__(256) void prep_flat(
    const void* __restrict__ A, const void* __restrict__ Bm,
    float* __restrict__ Bt, float* __restrict__ Afp)
{
    const bool ab = detect_bf16(A);
    const bool bb = detect_bf16(Bm);
    const int i = blockIdx.x * 256 + threadIdx.x;
    if (i < KF * Rr) {
        const int k = i >> 4, r = i & 15;
        Bt[i] = bb ? bf16_bits(((const unsigned short*)Bm)[r * KF + k])
                   : ((const float*)Bm)[r * KF + k];
    }
    if (i < Oo * Rr) {
        Afp[i] = ab ? bf16_bits(((const unsigned short*)A)[i])
                    : ((const float*)A)[i];
    }
}

#define CONV_BODY(CC, XBUF)                                                  \
    {                                                                        \
        float xv[HB + 2];                                                    \
        _Pragma("unroll")                                                    \
        for (int rr = 0; rr < HB + 2; ++rr) xv[rr] = XBUF[rr];               \
        const int ccn = ((CC) + 4 < 32) ? (CC) + 4 : (CC);                   \
        const unsigned coffn = (unsigned)(ccn * Ll);                         \
        _Pragma("unroll")                                                    \
        for (int rr = 0; rr < HB + 2; ++rr) {                                \
            const float v = ld<XB>(x, rowb[rr] + coffn);                     \
            XBUF[rr] = hv[rr] ? v : 0.f;                                     \
        }                                                                    \
        const float* bt = btb + (size_t)((CC) * 9) * Rr;                     \
        _Pragma("unroll")                                                    \
        for (int dh = 0; dh < 3; ++dh) {                                     \
            const float x0 = xv[dh];                                         \
            const float x1 = xv[dh + 1];                                     \
            _Pragma("unroll")                                                \
            for (int dw = 0; dw < 3; ++dw) {                                 \
                const float* bp = bt + (dh * 3 + dw) * Rr;                   \
                _Pragma("unroll")                                            \
                for (int j = 0; j < 8; ++j) {                                \
                    const float bv = bp[j];                                  \
                    a[0][dw][j] += bv * x0;                                  \
                    a[1][dw][j] += bv * x1;                                  \
                }                                                            \
            }                                                                \
        }                                                                    \
    }

template<bool XB>
__device__ __forceinline__ void mid_body(
    const void* __restrict__ x,
    const float* __restrict__ Bt,
    const float* __restrict__ Afp,
    float* __restrict__ out,
    float (* __restrict__ part)[4][Rr][64],
    float (* __restrict__ tmp2)[64][17])
{
    const int tid  = threadIdx.x;
    const int lane = tid & 63;
    const int wv   = __builtin_amdgcn_readfirstlane(tid >> 6);
    const int cs   = wv & 3;
    const int rh   = wv >> 2;
    const int h0   = blockIdx.x * HB;
    const int b    = blockIdx.y;
    const int w    = lane;
    const bool wok = (w < Ww);
    const int  wcl = wok ? w : (Ww - 1);

    float a[HB][3][8];
#pragma unroll
    for (int row = 0; row < HB; ++row)
#pragma unroll
        for (int dw = 0; dw < 3; ++dw)
#pragma unroll
            for (int j = 0; j < 8; ++j) a[row][dw][j] = 0.f;

    const unsigned xbase = (unsigned)(b * Cc * Ll + (cs * 32) * Ll);
    const float* btb = Bt + (size_t)(cs * 32 * 9) * Rr + rh * 8;

    unsigned rowb[HB + 2];
    bool     hv[HB + 2];
#pragma unroll
    for (int rr = 0; rr < HB + 2; ++rr) {
        const int hh  = h0 - 1 + rr;
        hv[rr] = (hh >= 0) & (hh < Hh);
        const int hcl = hv[rr] ? hh : (hh < 0 ? 0 : Hh - 1);
        rowb[rr] = xbase + (unsigned)(hcl * Ww) + (unsigned)wcl;
    }

    float xb0[HB + 2], xb1[HB + 2], xb2[HB + 2], xb3[HB + 2];
#pragma unroll
    for (int rr = 0; rr < HB + 2; ++rr) {
        const float v0 = ld<XB>(x, rowb[rr]);
        xb0[rr] = hv[rr] ? v0 : 0.f;
        const float v1 = ld<XB>(x, rowb[rr] + (unsigned)Ll);
        xb1[rr] = hv[rr] ? v1 : 0.f;
        const float v2 = ld<XB>(x, rowb[rr] + (unsigned)(2 * Ll));
        xb2[rr] = hv[rr] ? v2 : 0.f;
        const float v3 = ld<XB>(x, rowb[rr] + (unsigned)(3 * Ll));
        xb3[rr] = hv[rr] ? v3 : 0.f;
    }
    for (int t = 0; t < 8; ++t) {
        CONV_BODY(4 * t,     xb0)
        CONV_BODY(4 * t + 1, xb1)
        CONV_BODY(4 * t + 2, xb2)
        CONV_BODY(4 * t + 3, xb3)
    }

#pragma unroll
    for (int row = 0; row < HB; ++row)
#pragma unroll
    for (int j = 0; j < 8; ++j) {
        const float up = __shfl(a[row][0][j], w - 1);
        const float dn = __shfl(a[row][2][j], w + 1);
        float s = a[row][1][j];
        s += (w > 0)      ? up : 0.f;
        s += (w < Ww - 1) ? dn : 0.f;
        part[row][cs][rh * 8 + j][lane] = s;
    }
    __syncthreads();
    {
        const int px = tid & 63;
        const int rr = (tid >> 6) & 7;
#pragma unroll
        for (int row = 0; row < HB; ++row)
#pragma unroll
        for (int t = 0; t < 2; ++t) {
            const int r = rr + t * 8;
            tmp2[row][px][r] = part[row][0][r][px] + part[row][1][r][px]
                             + part[row][2][r][px] + part[row][3][r][px];
        }
    }
    __syncthreads();

    float tv[HB][Rr];
#pragma unroll
    for (int row = 0; row < HB; ++row)
#pragma unroll
        for (int r = 0; r < Rr; ++r) tv[row][r] = tmp2[row][lane][r];

    const size_t obase = (size_t)b * Oo * Ll + (size_t)(h0 * Ww) + (size_t)w;
#pragma unroll 4
    for (int j = 0; j < 32; ++j) {
        const int o = wv * 32 + j;
        const float* Ao = Afp + (size_t)o * Rr;
        float s0 = 0.f, s1 = 0.f;
#pragma unroll
        for (int r = 0; r < Rr; ++r) {
            const float av = Ao[r];
            s0 += av * tv[0][r];
            s1 += av * tv[1][r];
        }
        if (wok) {
            out[obase + (size_t)o * Ll]      = s0;
            out[obase + (size_t)o * Ll + Ww] = s1;
        }
    }
}

__global__ __launch_bounds__(512, 4) void fused_mid(
    const void* __restrict__ x,
    const float* __restrict__ Bt,
    const float* __restrict__ Afp,
    float* __restrict__ out)
{
    __shared__ float part[HB][4][Rr][64];
    __shared__ float tmp2[HB][64][17];
    if (detect_bf16(x)) mid_body<true >(x, Bt, Afp, out, part, tmp2);
    else                mid_body<false>(x, Bt, Afp, out, part, tmp2);
}

// ---- fallback (ws too small): slow but correct, no workspace.
__global__ __launch_bounds__(256) void fused_fallback(
    const void* __restrict__ x, const void* __restrict__ A,
    const void* __restrict__ Bm, float* __restrict__ out)
{
    const bool xb = detect_bf16(x);
    const bool ab = detect_bf16(A);
    const bool bb = detect_bf16(Bm);
    const int gid = blockIdx.x * 256 + threadIdx.x;
    const int b = gid / Ll;
    const int l = gid - b * Ll;
    const int h = l / Ww, w = l - h * Ww;
    float acc[Rr];
#pragma unroll
    for (int r = 0; r < Rr; ++r) acc[r] = 0.f;
    const size_t xbase = (size_t)b * Cc * Ll;
    for (int c = 0; c < Cc; ++c) {
        const size_t xc = xbase + (size_t)c * Ll;
        float xv[9];
#pragma unroll
        for (int dh = 0; dh < 3; ++dh) {
            const int hh = h + dh - 1;
            const bool hok = (hh >= 0) & (hh < Hh);
#pragma unroll
            for (int dw = 0; dw < 3; ++dw) {
                const int ww = w + dw - 1;
                const bool ok = hok & (ww >= 0) & (ww < Ww);
                const size_t idx = xc + (size_t)(hh * Ww + ww);
                xv[dh*3+dw] = ok ? (xb ? bf16_bits(((const unsigned short*)x)[idx])
                                       : ((const float*)x)[idx]) : 0.f;
            }
        }
#pragma unroll
        for (int r = 0; r < Rr; ++r) {
            const size_t bo = (size_t)r * KF + (size_t)c * 9;
            float s = acc[r];
#pragma unroll
            for (int i = 0; i < 9; ++i)
                s += (bb ? bf16_bits(((const unsigned short*)Bm)[bo+i])
                         : ((const float*)Bm)[bo+i]) * xv[i];
            acc[r] = s;
        }
    }
    const size_t obase = (size_t)b * Oo * Ll + (size_t)l;
    for (int o = 0; o < Oo; ++o) {
        float s = 0.f;
#pragma unroll
        for (int r = 0; r < Rr; ++r)
            s += (ab ? bf16_bits(((const unsigned short*)A)[o*Rr+r])
                     : ((const float*)A)[o*Rr+r]) * acc[r];
        out[obase + (size_t)o * Ll] = s;
    }
}

extern "C" void kernel_launch(void* const* d_in, const int* in_sizes, int n_in,
                              void* d_out, int out_size, void* d_ws, size_t ws_size,
                              hipStream_t stream) {
    const void* x  = d_in[0];
    const void* A  = d_in[1];
    const void* Bm = d_in[2];
    for (int i = 0; i < n_in && i < 3; ++i) {
        const int s = in_sizes[i];
        if      (s == Bn * Cc * Ll) x  = d_in[i];
        else if (s == Oo * Rr)      A  = d_in[i];
        else if (s == Rr * KF)      Bm = d_in[i];
    }
    float* out = (float*)d_out;

    const size_t frag_bytes = (size_t)(NKS * 2 * 512) * 2;          // 73728
    const size_t afp_bytes  = (size_t)(Oo * Rr) * 4;                // 16384
    const size_t xt_bytes   = (size_t)Bn * H2 * W2 * Cc * 2;        // 13778944
    const size_t need_big   = frag_bytes + afp_bytes + xt_bytes;    // ~13.87 MB
    const size_t need_mid   = frag_bytes + afp_bytes;               // 90112

    if (ws_size >= need_big) {
        unsigned short* Bfrag = (unsigned short*)d_ws;
        float* Afp = (float*)((char*)d_ws + frag_bytes);
        unsigned short* xt = (unsigned short*)((char*)d_ws + frag_bytes + afp_bytes);
        prep_frag<<<dim3(72), 256, 0, stream>>>(A, Bm, Bfrag, Afp);
        transpose_x<<<dim3(H2, Bn), 256, 0, stream>>>(x, xt);
        fused_mfma2<<<dim3(Hh, Bn), 256, 0, stream>>>(xt, Bfrag, Afp, out);
    } else if (ws_size >= need_mid) {
        float* Bt  = (float*)d_ws;
        float* Afp = Bt + KF * Rr;
        prep_flat<<<dim3((KF * Rr + 255) / 256), 256, 0, stream>>>(A, Bm, Bt, Afp);
        fused_mid<<<dim3(Hh / HB, Bn), 512, 0, stream>>>(x, Bt, Afp, out);
    } else {
        fused_fallback<<<dim3((Bn * Ll) / 256), 256, 0, stream>>>(x, A, Bm, out);
    }
}

// Round 9
// 116.394 us; speedup vs baseline: 1.1816x; 1.1816x over previous
//
#include <hip/hip_runtime.h>
#include <hip/hip_bf16.h>

// LoRA-factored 3x3 conv. out fp32. Input dtypes runtime-detected.
// x: [16,128,56,56], A: [256,16], B: [16,1152] -> out: [16,256,56,56]
// R13: ONE fused kernel. R12's global transpose (xt write+read round trip,
// ~69us total kernels) is folded into LDS: block stages 4 x-rows as
// [px][c] bf16 (58px x 256B x 4 = 59.4KB) with 16B-slot XOR swizzle
// (slot^(px&7)) so MFMA-operand ds_read_b128 (256B lane stride) is
// bank-uniform; pitch stays 256B -> all b128 reads 16B-aligned. Per K-step:
// 1 Bfrag hi/lo pair (shared by both output rows) + 2 ds_read_b128 +
// 4 MFMA. Stage-2 = proven fp32 epilogue, tmp overlaid on xs post-barrier.
// Grid 28x16=448 blocks, 256thr, 2 blocks/CU -> single round.
// Proven carried: Bfrag hi/lo frag-order prep (R11/12), C layout
// col=lane&15,row=(lane>>4)*4+reg (R11/12 passed), dtype detect (R3).

#define Bn 16
#define Cc 128
#define Hh 56
#define Ww 56
#define Ll (Hh * Ww)      // 3136
#define Rr 16
#define Oo 256
#define KF (Cc * 9)       // 1152
#define NKS 36            // K-steps: 1152/32
#define W2 58             // padded px range
#define RPITCH 128        // u16 per pixel in LDS (=256B, no pad)
#define ROWB (W2 * RPITCH) // 7424 u16 per staged row
#define HB 2              // output rows per block

typedef __attribute__((ext_vector_type(8))) short bfrag_t;  // 8 bf16
typedef __attribute__((ext_vector_type(4))) float f32x4;    // C frag

__device__ __forceinline__ float bf16_bits(unsigned short u) {
    return __uint_as_float(((unsigned)u) << 16);
}

__device__ __forceinline__ unsigned short bf16_rne(float f) {
    const unsigned u = __float_as_uint(f);
    const unsigned r = u + 0x7FFFu + ((u >> 16) & 1u);
    return (unsigned short)(r >> 16);
}

// bf16-packed detect (proven R3).
__device__ __forceinline__ bool detect_bf16(const void* __restrict__ p) {
    const unsigned* w = (const unsigned*)p;
    int c = 0;
#pragma unroll
    for (int i = 0; i < 32; ++i) {
        const unsigned e = (w[i] >> 7) & 0xFFu;
        c += (e >= 96u && e <= 144u) ? 1 : 0;
    }
    return c >= 20;
}

// swizzled u16 index for (px, c) within one staged row
__device__ __forceinline__ int sw_idx(int px, int c) {
    return px * RPITCH + (((c >> 3) ^ (px & 7)) << 3) + (c & 7);
}

// ---- prep: Bfrag[kstep][hi/lo][lane][8e] bf16 (frag order, tap-major K),
//      Afp[o][r] fp32. (Unchanged from R11/R12 - harness-verified.)
__global__ __launch_bounds__(256) void prep_frag(
    const void* __restrict__ A, const void* __restrict__ Bm,
    unsigned short* __restrict__ Bfrag, float* __restrict__ Afp)
{
    const bool ab = detect_bf16(A);
    const bool bb = detect_bf16(Bm);
    const int i = blockIdx.x * 256 + threadIdx.x;
    if (i < NKS * 512) {
        const int kstep = i >> 9, rem = i & 511;
        const int l = rem >> 3, e = rem & 7;
        const int r = l & 15, g = l >> 4;
        const int kp = kstep * 32 + g * 8 + e;   // tap-major k'
        const int tap = kp >> 7, c = kp & 127;
        const int k = c * 9 + tap;               // torch Unfold order (c,kh,kw)
        const float v = bb ? bf16_bits(((const unsigned short*)Bm)[r * KF + k])
                           : ((const float*)Bm)[r * KF + k];
        const unsigned short hi = bf16_rne(v);
        const float lov = v - bf16_bits(hi);
        Bfrag[(kstep * 2 + 0) * 512 + rem] = hi;
        Bfrag[(kstep * 2 + 1) * 512 + rem] = bf16_rne(lov);
    }
    if (i < Oo * Rr) {
        Afp[i] = ab ? bf16_bits(((const unsigned short*)A)[i])
                    : ((const float*)A)[i];
    }
}

// ---- fused main: one block = (b, rows h0,h0+1). 4 waves = 4 px-tiles.
template<bool XB>
__device__ __forceinline__ void fused_body(
    const void* __restrict__ x,
    const unsigned short* __restrict__ Bfrag,
    const float* __restrict__ Afp,
    float* __restrict__ out,
    unsigned short* __restrict__ xs)      // [4*ROWB] u16, 59392 B
{
    const int tid  = threadIdx.x;
    const int lane = tid & 63;
    const int wv   = __builtin_amdgcn_readfirstlane(tid >> 6);  // px-tile 0..3
    const int col  = lane & 15;
    const int g    = lane >> 4;
    const int h0   = blockIdx.x * HB;
    const int b    = blockIdx.y;

    // ---- stage 4 x-rows (h0-1 .. h0+2) into swizzled LDS [px][c]
#pragma unroll
    for (int rr = 0; rr < HB + 2; ++rr) {
        const int hh = h0 - 1 + rr;
        unsigned short* xr = xs + rr * ROWB;
        if (hh >= 0 && hh < Hh) {
#pragma unroll
            for (int it = 0; it < 16; ++it) {
                const int idx = it * 256 + tid;       // 4096 = 128c x 32wp
                const int wp = idx & 31, c = idx >> 5;
                if (wp < 28) {
                    unsigned short lo, hi;
                    if constexpr (XB) {
                        const unsigned v = ((const unsigned*)x)[
                            (unsigned)((b * Cc + c) * (Ll / 2) + hh * (Ww / 2) + wp)];
                        lo = (unsigned short)(v & 0xFFFFu);
                        hi = (unsigned short)(v >> 16);
                    } else {
                        const unsigned base =
                            (unsigned)((b * Cc + c) * Ll + hh * Ww + 2 * wp);
                        lo = bf16_rne(((const float*)x)[base]);
                        hi = bf16_rne(((const float*)x)[base + 1]);
                    }
                    xr[sw_idx(2 * wp + 1, c)] = lo;   // px = w+1
                    xr[sw_idx(2 * wp + 2, c)] = hi;
                }
            }
            // zero w-borders (px=0, px=57): all 128 u16 covers any swizzle
            if (tid < 128) {
                xr[tid] = 0;
                xr[57 * RPITCH + tid] = 0;
            }
        } else {
            // zero whole row: 3712 dwords
#pragma unroll
            for (int it = 0; it < 15; ++it) {
                const int idx = it * 256 + tid;
                ((unsigned*)xr)[idx] = 0u;
            }
            if (tid < 3712 - 15 * 256) ((unsigned*)xr)[15 * 256 + tid] = 0u;
        }
    }
    __syncthreads();

    // ---- stage 1: MFMA over K=1152 (36 steps x hi/lo), both rows share Bfrag
    const int px  = wv * 16 + col;              // output pixel w (valid < 56)
    const int pxc = px < Ww ? px : Ww - 1;      // clamp lanes 56..63 (masked)

    // 12 per-lane swizzled LDS offsets (u16 units): [dw][cb]
    unsigned off12[12];
#pragma unroll
    for (int dwv = 0; dwv < 3; ++dwv) {
#pragma unroll
        for (int cb = 0; cb < 4; ++cb) {
            const int p2 = pxc + dwv;
            off12[dwv * 4 + cb] =
                (unsigned)(p2 * RPITCH + ((((cb * 4 + g) ^ (p2 & 7))) << 3));
        }
    }

    f32x4 acc0 = {0.f, 0.f, 0.f, 0.f};
    f32x4 acc1 = {0.f, 0.f, 0.f, 0.f};
    const bfrag_t* __restrict__ bf = (const bfrag_t*)Bfrag;

#pragma unroll
    for (int ks = 0; ks < NKS; ++ks) {
        const int tap = ks >> 2, cb = ks & 3;
        const int dh = tap / 3, dw = tap - dh * 3;
        const bfrag_t ahi = bf[(ks * 2 + 0) * 64 + lane];  // coalesced 16B/lane
        const bfrag_t alo = bf[(ks * 2 + 1) * 64 + lane];
        const unsigned short* p0 = xs + dh * ROWB + off12[dw * 4 + cb];
        const bfrag_t pf0 = *(const bfrag_t*)p0;           // 16B-aligned
        const bfrag_t pf1 = *(const bfrag_t*)(p0 + ROWB);  // row h0+1
        acc0 = __builtin_amdgcn_mfma_f32_16x16x32_bf16(ahi, pf0, acc0, 0, 0, 0);
        acc0 = __builtin_amdgcn_mfma_f32_16x16x32_bf16(alo, pf0, acc0, 0, 0, 0);
        acc1 = __builtin_amdgcn_mfma_f32_16x16x32_bf16(ahi, pf1, acc1, 0, 0, 0);
        acc1 = __builtin_amdgcn_mfma_f32_16x16x32_bf16(alo, pf1, acc1, 0, 0, 0);
    }

    // ---- LDS reuse: overlay tmp on xs (stage-1 reads complete after barrier)
    __syncthreads();
    float (*tmp)[Rr][66] = (float (*)[Rr][66])xs;   // 2x16x66x4 = 8448 B

    // C layout: col=lane&15 (px), row=(lane>>4)*4+reg  [R11/R12-verified]
#pragma unroll
    for (int reg = 0; reg < 4; ++reg) {
        tmp[0][g * 4 + reg][wv * 16 + col] = acc0[reg];
        tmp[1][g * 4 + reg][wv * 16 + col] = acc1[reg];
    }
    __syncthreads();

    // ---- stage 2 (proven fp32 epilogue): wave wv emits o = wv*64 .. +63
    float tv0[Rr], tv1[Rr];
#pragma unroll
    for (int r = 0; r < Rr; ++r) {
        tv0[r] = tmp[0][r][lane];
        tv1[r] = tmp[1][r][lane];
    }

    const bool wok = (lane < Ww);
    const size_t obase = (size_t)b * Oo * Ll + (size_t)(h0 * Ww) + (size_t)lane;
#pragma unroll 4
    for (int j = 0; j < 64; ++j) {
        const int o = wv * 64 + j;
        const float* Ao = Afp + (size_t)o * Rr;   // uniform -> s_load
        float s0 = 0.f, s1 = 0.f;
#pragma unroll
        for (int r = 0; r < Rr; ++r) {
            const float av = Ao[r];
            s0 += av * tv0[r];
            s1 += av * tv1[r];
        }
        if (wok) {
            out[obase + (size_t)o * Ll]      = s0;
            out[obase + (size_t)o * Ll + Ww] = s1;
        }
    }
}

__global__ __launch_bounds__(256, 2) void fused_one(
    const void* __restrict__ x,
    const unsigned short* __restrict__ Bfrag,
    const float* __restrict__ Afp,
    float* __restrict__ out)
{
    __shared__ __align__(16) unsigned short xs[4 * ROWB];   // 59392 B
    if (detect_bf16(x)) fused_body<true >(x, Bfrag, Afp, out, xs);
    else                fused_body<false>(x, Bfrag, Afp, out, xs);
}

// ---- fallback (ws too small): slow but correct, no workspace.
__global__ __launch_bounds__(256) void fused_fallback(
    const void* __restrict__ x, const void* __restrict__ A,
    const void* __restrict__ Bm, float* __restrict__ out)
{
    const bool xb = detect_bf16(x);
    const bool ab = detect_bf16(A);
    const bool bb = detect_bf16(Bm);
    const int gid = blockIdx.x * 256 + threadIdx.x;
    const int b = gid / Ll;
    const int l = gid - b * Ll;
    const int h = l / Ww, w = l - h * Ww;
    float acc[Rr];
#pragma unroll
    for (int r = 0; r < Rr; ++r) acc[r] = 0.f;
    const size_t xbase = (size_t)b * Cc * Ll;
    for (int c = 0; c < Cc; ++c) {
        const size_t xc = xbase + (size_t)c * Ll;
        float xv[9];
#pragma unroll
        for (int dh = 0; dh < 3; ++dh) {
            const int hh = h + dh - 1;
            const bool hok = (hh >= 0) & (hh < Hh);
#pragma unroll
            for (int dw = 0; dw < 3; ++dw) {
                const int ww = w + dw - 1;
                const bool ok = hok & (ww >= 0) & (ww < Ww);
                const size_t idx = xc + (size_t)(hh * Ww + ww);
                xv[dh*3+dw] = ok ? (xb ? bf16_bits(((const unsigned short*)x)[idx])
                                       : ((const float*)x)[idx]) : 0.f;
            }
        }
#pragma unroll
        for (int r = 0; r < Rr; ++r) {
            const size_t bo = (size_t)r * KF + (size_t)c * 9;
            float s = acc[r];
#pragma unroll
            for (int i = 0; i < 9; ++i)
                s += (bb ? bf16_bits(((const unsigned short*)Bm)[bo+i])
                         : ((const float*)Bm)[bo+i]) * xv[i];
            acc[r] = s;
        }
    }
    const size_t obase = (size_t)b * Oo * Ll + (size_t)l;
    for (int o = 0; o < Oo; ++o) {
        float s = 0.f;
#pragma unroll
        for (int r = 0; r < Rr; ++r)
            s += (ab ? bf16_bits(((const unsigned short*)A)[o*Rr+r])
                     : ((const float*)A)[o*Rr+r]) * acc[r];
        out[obase + (size_t)o * Ll] = s;
    }
}

extern "C" void kernel_launch(void* const* d_in, const int* in_sizes, int n_in,
                              void* d_out, int out_size, void* d_ws, size_t ws_size,
                              hipStream_t stream) {
    const void* x  = d_in[0];
    const void* A  = d_in[1];
    const void* Bm = d_in[2];
    for (int i = 0; i < n_in && i < 3; ++i) {
        const int s = in_sizes[i];
        if      (s == Bn * Cc * Ll) x  = d_in[i];
        else if (s == Oo * Rr)      A  = d_in[i];
        else if (s == Rr * KF)      Bm = d_in[i];
    }
    float* out = (float*)d_out;

    const size_t frag_bytes = (size_t)(NKS * 2 * 512) * 2;          // 73728
    const size_t afp_bytes  = (size_t)(Oo * Rr) * 4;                // 16384
    const size_t need       = frag_bytes + afp_bytes;               // 90112

    if (ws_size >= need) {
        unsigned short* Bfrag = (unsigned short*)d_ws;
        float* Afp = (float*)((char*)d_ws + frag_bytes);
        prep_frag<<<dim3(72), 256, 0, stream>>>(A, Bm, Bfrag, Afp);
        fused_one<<<dim3(Hh / HB, Bn), 256, 0, stream>>>(x, Bfrag, Afp, out);
    } else {
        fused_fallback<<<dim3((Bn * Ll) / 256), 256, 0, stream>>>(x, A, Bm, out);
    }
}

// Round 11
// 103.526 us; speedup vs baseline: 1.3285x; 1.1243x over previous
//
#include <hip/hip_runtime.h>
#include <hip/hip_bf16.h>

// LoRA-factored 3x3 conv. out fp32. Input dtypes runtime-detected.
// x: [16,128,56,56], A: [256,16], B: [16,1152] -> out: [16,256,56,56]
// R15 = R13 (44.1us, PASSED, counters: occ 14.9%, 3.07M conflicts) with two
// targeted fixes; R14's tr-read layout model failed correctness (absmax 5.6)
// and is abandoned.
//  (1) 512-thr blocks: 8 waves = 4 px-tiles x 2 K-halves (cb-pair split).
//      Same 59.4KB LDS -> still 2 blocks/CU but 4 waves/SIMD (2x R13).
//      Partial C reduced via tmp2[2][2][16][66] LDS overlay (16.9KB).
//  (2) staging: 8 coalesced u16 channel-row loads -> ONE ds_write_b128 per
//      (cslot,row) task. Per thread: 64 loads + 8 b128 writes + 8 addr
//      (was 64 + 128 scalar b16 + 128 addr). Conflicts -> ~bandwidth floor.
// Verified carried bytes: swizzled [px][c] layout (slot^(px&7), pitch 256B),
// b128 read addressing (off6 == R13 off12 restricted), Bfrag hi/lo frag
// order (R11-13), C layout col=lane&15,row=(lane>>4)*4+reg, fp32 stage-2,
// detect (R3).

#define Bn 16
#define Cc 128
#define Hh 56
#define Ww 56
#define Ll (Hh * Ww)      // 3136
#define Rr 16
#define Oo 256
#define KF (Cc * 9)       // 1152
#define NKS 36            // K-steps: 1152/32
#define W2 58             // padded px range
#define RPITCH 128        // u16 per pixel in LDS (=256B, no pad)
#define ROWB (W2 * RPITCH) // 7424 u16 per staged row
#define HB 2              // output rows per block

typedef __attribute__((ext_vector_type(8))) short bfrag_t;  // 8 bf16 (16B)
typedef __attribute__((ext_vector_type(4))) float f32x4;    // C frag

__device__ __forceinline__ float bf16_bits(unsigned short u) {
    return __uint_as_float(((unsigned)u) << 16);
}

__device__ __forceinline__ unsigned short bf16_rne(float f) {
    const unsigned u = __float_as_uint(f);
    const unsigned r = u + 0x7FFFu + ((u >> 16) & 1u);
    return (unsigned short)(r >> 16);
}

// bf16-packed detect (proven R3).
__device__ __forceinline__ bool detect_bf16(const void* __restrict__ p) {
    const unsigned* w = (const unsigned*)p;
    int c = 0;
#pragma unroll
    for (int i = 0; i < 32; ++i) {
        const unsigned e = (w[i] >> 7) & 0xFFu;
        c += (e >= 96u && e <= 144u) ? 1 : 0;
    }
    return c >= 20;
}

// ---- prep: Bfrag[kstep][hi/lo][lane][8e] bf16 (frag order, tap-major K),
//      Afp[o][r] fp32. (Unchanged from R11-R13 - harness-verified.)
__global__ __launch_bounds__(256) void prep_frag(
    const void* __restrict__ A, const void* __restrict__ Bm,
    unsigned short* __restrict__ Bfrag, float* __restrict__ Afp)
{
    const bool ab = detect_bf16(A);
    const bool bb = detect_bf16(Bm);
    const int i = blockIdx.x * 256 + threadIdx.x;
    if (i < NKS * 512) {
        const int kstep = i >> 9, rem = i & 511;
        const int l = rem >> 3, e = rem & 7;
        const int r = l & 15, g = l >> 4;
        const int kp = kstep * 32 + g * 8 + e;   // tap-major k'
        const int tap = kp >> 7, c = kp & 127;
        const int k = c * 9 + tap;               // torch Unfold order (c,kh,kw)
        const float v = bb ? bf16_bits(((const unsigned short*)Bm)[r * KF + k])
                           : ((const float*)Bm)[r * KF + k];
        const unsigned short hi = bf16_rne(v);
        const float lov = v - bf16_bits(hi);
        Bfrag[(kstep * 2 + 0) * 512 + rem] = hi;
        Bfrag[(kstep * 2 + 1) * 512 + rem] = bf16_rne(lov);
    }
    if (i < Oo * Rr) {
        Afp[i] = ab ? bf16_bits(((const unsigned short*)A)[i])
                    : ((const float*)A)[i];
    }
}

#define MFB(A, B, C) __builtin_amdgcn_mfma_f32_16x16x32_bf16((A), (B), (C), 0, 0, 0)

// ---- fused main: one block = (b, rows h0,h0+1). 8 waves = 4 px-tiles x 2 K-halves.
template<bool XB>
__device__ __forceinline__ void fused_body(
    const void* __restrict__ x,
    const unsigned short* __restrict__ Bfrag,
    const float* __restrict__ Afp,
    float* __restrict__ out,
    unsigned short* __restrict__ xs)      // [4*ROWB] u16, 59392 B
{
    const int tid  = threadIdx.x;
    const int lane = tid & 63;
    const int wv   = __builtin_amdgcn_readfirstlane(tid >> 6);  // wave 0..7
    const int t    = wv & 3;              // px-tile 0..3
    const int kh   = wv >> 2;             // K-half 0..1 (cb pair)
    const int h0   = blockIdx.x * HB;
    const int b    = blockIdx.y;

    // ---- stage 4 x-rows (h0-1 .. h0+2) into swizzled LDS [px][c].
    // Per (row, cslot) task: lane l (w=l, px=l+1) loads 8 consecutive
    // channels (8 coalesced u16 row-loads) -> ONE ds_write_b128 at
    // byte = px*256 + ((cslot ^ (px&7))<<4). 64 tasks / 8 waves.
    {
        const int l   = lane;
        const bool lok = (l < Ww);
#pragma unroll
        for (int rr = 0; rr < HB + 2; ++rr) {
            const int hh = h0 - 1 + rr;
            unsigned short* xr = xs + rr * ROWB;
            if (hh >= 0 && hh < Hh) {
                if (lok) {
                    const unsigned gb = (unsigned)(b * Cc * Ll + hh * Ww + l);
#pragma unroll
                    for (int it = 0; it < 2; ++it) {
                        const int cs_ = it * 8 + wv;     // cslot 0..15
                        const int c0  = cs_ * 8;
                        bfrag_t v;
#pragma unroll
                        for (int j = 0; j < 8; ++j) {
                            if constexpr (XB) {
                                v[j] = (short)((const unsigned short*)x)[
                                    gb + (unsigned)((c0 + j) * Ll)];
                            } else {
                                v[j] = (short)bf16_rne(((const float*)x)[
                                    gb + (unsigned)((c0 + j) * Ll)]);
                            }
                        }
                        const int sp = cs_ ^ ((l + 1) & 7);
                        *(bfrag_t*)((char*)xr + (l + 1) * 256 + sp * 16) = v;
                    }
                }
            } else {
                // zero whole row: 3712 dwords, 512 threads
                unsigned* xw = (unsigned*)xr;
#pragma unroll
                for (int it = 0; it < 7; ++it) xw[it * 512 + tid] = 0u;
                if (tid < 3712 - 7 * 512) xw[7 * 512 + tid] = 0u;
            }
        }
        // zero px borders (px=0, px=57) on all rows (covers any swizzle)
        if (tid < 128) {
#pragma unroll
            for (int rr = 0; rr < HB + 2; ++rr) {
                xs[rr * ROWB + tid] = 0;
                xs[rr * ROWB + 57 * RPITCH + tid] = 0;
            }
        }
    }
    __syncthreads();

    // ---- stage 1: MFMA over this wave's K-half (cb in {2kh, 2kh+1}).
    const int col = lane & 15;
    const int g   = lane >> 4;
    const int px  = t * 16 + col;              // output pixel w (valid < 56)
    const int pxc = px < Ww ? px : Ww - 1;     // clamp lanes' px 56..63

    // 6 per-lane swizzled LDS byte offsets: [dw][cbi]  (== R13 off12 subset)
    unsigned off6[6];
#pragma unroll
    for (int dwv = 0; dwv < 3; ++dwv)
#pragma unroll
        for (int cbi = 0; cbi < 2; ++cbi) {
            const int cb = kh * 2 + cbi;
            const int p2 = pxc + dwv;          // window px-index w..w+2
            off6[dwv * 2 + cbi] = (unsigned)(p2 * 256 +
                (((cb * 4 + g) ^ (p2 & 7)) << 4));
        }

    f32x4 acc0 = {0.f, 0.f, 0.f, 0.f};
    f32x4 acc1 = {0.f, 0.f, 0.f, 0.f};
    const bfrag_t* __restrict__ bfp = (const bfrag_t*)Bfrag;

#pragma unroll
    for (int tap = 0; tap < 9; ++tap) {
        const int dh = tap / 3, dw = tap - dh * 3;
#pragma unroll
        for (int cbi = 0; cbi < 2; ++cbi) {
            const int cb = kh * 2 + cbi;
            const int ks = tap * 4 + cb;
            const bfrag_t ahi = bfp[(ks * 2 + 0) * 64 + lane];  // 16B/lane L2
            const bfrag_t alo = bfp[(ks * 2 + 1) * 64 + lane];
            const char* p0 = (const char*)xs + dh * (ROWB * 2) + off6[dw * 2 + cbi];
            const bfrag_t pf0 = *(const bfrag_t*)p0;            // 16B aligned
            const bfrag_t pf1 = *(const bfrag_t*)(p0 + ROWB * 2);
            acc0 = MFB(ahi, pf0, acc0);
            acc0 = MFB(alo, pf0, acc0);
            acc1 = MFB(ahi, pf1, acc1);
            acc1 = MFB(alo, pf1, acc1);
        }
    }

    // ---- LDS reuse: overlay partial-C on xs; reduce K-halves; stage 2.
    __syncthreads();
    float (*tmp2)[HB][Rr][66] = (float (*)[HB][Rr][66])xs;  // [2][2][16][66]

    // C layout: col=lane&15 (px), row=(lane>>4)*4+reg  [R11-R13 verified]
#pragma unroll
    for (int reg = 0; reg < 4; ++reg) {
        tmp2[kh][0][g * 4 + reg][t * 16 + col] = acc0[reg];
        tmp2[kh][1][g * 4 + reg][t * 16 + col] = acc1[reg];
    }
    __syncthreads();

    float tv0[Rr], tv1[Rr];
#pragma unroll
    for (int r = 0; r < Rr; ++r) {
        tv0[r] = tmp2[0][0][r][lane] + tmp2[1][0][r][lane];
        tv1[r] = tmp2[0][1][r][lane] + tmp2[1][1][r][lane];
    }

    const bool wok = (lane < Ww);
    const size_t obase = (size_t)b * Oo * Ll + (size_t)(h0 * Ww) + (size_t)lane;
#pragma unroll 4
    for (int j = 0; j < 32; ++j) {
        const int o = wv * 32 + j;                 // 8 waves x 32 = 256
        const float* Ao = Afp + (size_t)o * Rr;    // uniform -> s_load
        float s0 = 0.f, s1 = 0.f;
#pragma unroll
        for (int r = 0; r < Rr; ++r) {
            const float av = Ao[r];
            s0 += av * tv0[r];
            s1 += av * tv1[r];
        }
        if (wok) {
            out[obase + (size_t)o * Ll]      = s0;
            out[obase + (size_t)o * Ll + Ww] = s1;
        }
    }
}

__global__ __launch_bounds__(512, 4) void fused_ks(
    const void* __restrict__ x,
    const unsigned short* __restrict__ Bfrag,
    const float* __restrict__ Afp,
    float* __restrict__ out)
{
    __shared__ __align__(16) unsigned short xs[4 * ROWB];   // 59392 B
    if (detect_bf16(x)) fused_body<true >(x, Bfrag, Afp, out, xs);
    else                fused_body<false>(x, Bfrag, Afp, out, xs);
}

// ---- fallback (ws too small): slow but correct, no workspace.
__global__ __launch_bounds__(256) void fused_fallback(
    const void* __restrict__ x, const void* __restrict__ A,
    const void* __restrict__ Bm, float* __restrict__ out)
{
    const bool xb = detect_bf16(x);
    const bool ab = detect_bf16(A);
    const bool bb = detect_bf16(Bm);
    const int gid = blockIdx.x * 256 + threadIdx.x;
    const int b = gid / Ll;
    const int l = gid - b * Ll;
    const int h = l / Ww, w = l - h * Ww;
    float acc[Rr];
#pragma unroll
    for (int r = 0; r < Rr; ++r) acc[r] = 0.f;
    const size_t xbase = (size_t)b * Cc * Ll;
    for (int c = 0; c < Cc; ++c) {
        const size_t xc = xbase + (size_t)c * Ll;
        float xv[9];
#pragma unroll
        for (int dh = 0; dh < 3; ++dh) {
            const int hh = h + dh - 1;
            const bool hok = (hh >= 0) & (hh < Hh);
#pragma unroll
            for (int dw = 0; dw < 3; ++dw) {
                const int ww = w + dw - 1;
                const bool ok = hok & (ww >= 0) & (ww < Ww);
                const size_t idx = xc + (size_t)(hh * Ww + ww);
                xv[dh*3+dw] = ok ? (xb ? bf16_bits(((const unsigned short*)x)[idx])
                                       : ((const float*)x)[idx]) : 0.f;
            }
        }
#pragma unroll
        for (int r = 0; r < Rr; ++r) {
            const size_t bo = (size_t)r * KF + (size_t)c * 9;
            float s = acc[r];
#pragma unroll
            for (int i = 0; i < 9; ++i)
                s += (bb ? bf16_bits(((const unsigned short*)Bm)[bo+i])
                         : ((const float*)Bm)[bo+i]) * xv[i];
            acc[r] = s;
        }
    }
    const size_t obase = (size_t)b * Oo * Ll + (size_t)l;
    for (int o = 0; o < Oo; ++o) {
        float s = 0.f;
#pragma unroll
        for (int r = 0; r < Rr; ++r)
            s += (ab ? bf16_bits(((const unsigned short*)A)[o*Rr+r])
                     : ((const float*)A)[o*Rr+r]) * acc[r];
        out[obase + (size_t)o * Ll] = s;
    }
}

extern "C" void kernel_launch(void* const* d_in, const int* in_sizes, int n_in,
                              void* d_out, int out_size, void* d_ws, size_t ws_size,
                              hipStream_t stream) {
    const void* x  = d_in[0];
    const void* A  = d_in[1];
    const void* Bm = d_in[2];
    for (int i = 0; i < n_in && i < 3; ++i) {
        const int s = in_sizes[i];
        if      (s == Bn * Cc * Ll) x  = d_in[i];
        else if (s == Oo * Rr)      A  = d_in[i];
        else if (s == Rr * KF)      Bm = d_in[i];
    }
    float* out = (float*)d_out;

    const size_t frag_bytes = (size_t)(NKS * 2 * 512) * 2;          // 73728
    const size_t afp_bytes  = (size_t)(Oo * Rr) * 4;                // 16384
    const size_t need       = frag_bytes + afp_bytes;               // 90112

    if (ws_size >= need) {
        unsigned short* Bfrag = (unsigned short*)d_ws;
        float* Afp = (float*)((char*)d_ws + frag_bytes);
        prep_frag<<<dim3(72), 256, 0, stream>>>(A, Bm, Bfrag, Afp);
        fused_ks<<<dim3(Hh / HB, Bn), 512, 0, stream>>>(x, Bfrag, Afp, out);
    } else {
        fused_fallback<<<dim3((Bn * Ll) / 256), 256, 0, stream>>>(x, A, Bm, out);
    }
}